// Round 9
// baseline (57.868 us; speedup 1.0000x reference)
//
#include <hip/hip_runtime.h>
#include <math.h>

#define NS 1024
#define NU 32
#define ND 256
#define NROWS (NS * NU)             // 32768
#define BM 128                      // rows per k2 block
#define NBLK (NROWS / BM)           // 256 blocks, full 1024 cols each

static constexpr float EPS_POS = 1e-6f;
static constexpr float EPS_NEG = 1e-8f;

typedef __attribute__((ext_vector_type(8))) short bf16x8;
typedef __attribute__((ext_vector_type(4))) float f32x4;

#if __has_builtin(__builtin_amdgcn_exp2f)
#define EXP2F(x) __builtin_amdgcn_exp2f(x)
#else
#define EXP2F(x) exp2f(x)
#endif

static __device__ __forceinline__ unsigned short f2bf(float f) {
    union { float f; unsigned u; } v; v.f = f;
    unsigned r = v.u + 0x7fffu + ((v.u >> 16) & 1u);   // RNE
    return (unsigned short)(r >> 16);
}

// ---------------------------------------------------------------------------
// Kernel 1: per-speaker centroids (-> bf16 normalized cnb[t][d]), positive
// (LOO) cosines, and NORMALIZED bf16 ROWS dnb[r][d]. One block per speaker.
// ---------------------------------------------------------------------------
__global__ __launch_bounds__(256) void ge2e_k1(
    const float* __restrict__ dv, unsigned short* __restrict__ cnb,
    unsigned short* __restrict__ dnb, float* __restrict__ blk_pos)
{
    const int s = blockIdx.x;
    const int tid = threadIdx.x;
    const int wave = tid >> 6;
    const int lane = tid & 63;

    __shared__ float v[NU][ND];
    __shared__ float cs[ND];
    __shared__ float sinvs[NU];
    __shared__ float red[16];

    const float* base = dv + (size_t)s * (NU * ND);
    for (int idx = tid; idx < NU * ND; idx += 256) {
        v[idx >> 8][idx & 255] = base[idx];
    }
    __syncthreads();

    {
        float a = 0.f;
        #pragma unroll
        for (int u = 0; u < NU; ++u) a += v[u][tid];
        cs[tid] = a;
    }
    __syncthreads();

    // centroid norm -> normalized centroid in bf16, row-major [t][d]
    float c = cs[tid] * (1.0f / NU);
    float p = c * c;
    #pragma unroll
    for (int off = 32; off > 0; off >>= 1) p += __shfl_xor(p, off, 64);
    if (lane == 0) red[wave] = p;
    __syncthreads();
    if (tid == 0) red[8] = red[0] + red[1] + red[2] + red[3];
    __syncthreads();
    {
        float rn = 1.0f / fmaxf(sqrtf(red[8]), EPS_NEG);
        cnb[(size_t)s * ND + tid] = f2bf(c * rn);
    }

    // per-utterance stats: wave w handles u = 8w .. 8w+7
    const float inv31 = 1.0f / (NU - 1);
    float pos_part = 0.f;
    const float4 cc = *(const float4*)&cs[lane * 4];
    for (int uu = 0; uu < 8; ++uu) {
        const int u = wave * 8 + uu;
        const float4 vv = *(const float4*)&v[u][lane * 4];
        float pv = 0.f, pp = 0.f, px = 0.f;
        float pc;
        pc = (cc.x - vv.x) * inv31; pv += vv.x * vv.x; pp += pc * pc; px += vv.x * pc;
        pc = (cc.y - vv.y) * inv31; pv += vv.y * vv.y; pp += pc * pc; px += vv.y * pc;
        pc = (cc.z - vv.z) * inv31; pv += vv.z * vv.z; pp += pc * pc; px += vv.z * pc;
        pc = (cc.w - vv.w) * inv31; pv += vv.w * vv.w; pp += pc * pc; px += vv.w * pc;
        #pragma unroll
        for (int off = 32; off > 0; off >>= 1) {
            pv += __shfl_xor(pv, off, 64);
            pp += __shfl_xor(pp, off, 64);
            px += __shfl_xor(px, off, 64);
        }
        if (lane == 0) {
            float nv = sqrtf(pv), npc = sqrtf(pp);
            pos_part += px / (fmaxf(nv, EPS_POS) * fmaxf(npc, EPS_POS));
            sinvs[u] = 1.0f / fmaxf(nv, EPS_NEG);
        }
    }
    if (lane == 0) red[4 + wave] = pos_part;
    __syncthreads();
    if (tid == 0) blk_pos[s] = red[4] + red[5] + red[6] + red[7];

    // normalized bf16 rows -> global (coalesced 16B stores)
    #pragma unroll
    for (int it = 0; it < 4; ++it) {
        const int idx = it * 2048 + tid * 8;
        const int u = idx >> 8, d0 = idx & 255;
        const float sc = sinvs[u];
        uint4 pk;
        pk.x = (unsigned)f2bf(v[u][d0 + 0] * sc) | ((unsigned)f2bf(v[u][d0 + 1] * sc) << 16);
        pk.y = (unsigned)f2bf(v[u][d0 + 2] * sc) | ((unsigned)f2bf(v[u][d0 + 3] * sc) << 16);
        pk.z = (unsigned)f2bf(v[u][d0 + 4] * sc) | ((unsigned)f2bf(v[u][d0 + 5] * sc) << 16);
        pk.w = (unsigned)f2bf(v[u][d0 + 6] * sc) | ((unsigned)f2bf(v[u][d0 + 7] * sc) << 16);
        *(uint4*)&dnb[(size_t)s * (NU * ND) + idx] = pk;
    }
}

// ---------------------------------------------------------------------------
// Kernel 2: MFMA GEMM, BM=128 rows x ALL 1024 cols, K=256, with fused
// fixed-reference sum-exp epilogue. 256 blocks x 512 threads (8 waves =
// 2 mg x 4 ng, mt=4). afr[4][8] pinned in registers from dnb.
// T4 pipeline: 3 LDS buffers (32 KB each), depth-2 prefetch via
// global_load_lds w=16, COUNTED s_waitcnt vmcnt(8) + raw s_barrier per step
// (never drain to 0 in the loop). Each wave stages its own LDS quarter, so
// per-wave vmcnt counting + barrier => whole slab visible.
// ---------------------------------------------------------------------------
__global__ __launch_bounds__(512, 2) void ge2e_k2(
    const unsigned short* __restrict__ dnb, const unsigned short* __restrict__ cnb,
    const float* __restrict__ wp, const float* __restrict__ bp,
    float* __restrict__ blk_neg, float* __restrict__ blk_lse)
{
    const int blk = blockIdx.x;
    const int r0 = blk * BM;
    const int tid = threadIdx.x;
    const int w  = tid >> 6;
    const int l  = tid & 63;
    const int lr = l & 15;
    const int lg = l >> 4;
    const int mg = w >> 2;   // 0..1: rows mg*64 .. +64
    const int ng = w & 3;    // 0..3: cols j*64 + ng*16 .. +16
    const int rsw = lr & 7;

    __shared__ unsigned short Bst[3][64][256];   // 96 KB triple buffer
    __shared__ float pse[4][BM];
    __shared__ float psm[4][BM];
    __shared__ float redn[2], redl[2];

    const float w0 = wp[0];
    const float b0 = bp[0];
    const float c2 = w0 * 1.4426950408889634f;   // w0 * log2(e)

    // --- B stage addressing: per-lane pre-swizzled global src, linear LDS.
    // Slab = 64 cols x 256 k = 32 KB = 2048 granules of 16B; 512 thr x 4.
    unsigned srcb[4], ldso[4];
    #pragma unroll
    for (int i = 0; i < 4; ++i) {
        const int gi = w * 256 + i * 64 + l;   // granule 0..2047 of the slab
        const int rr = gi >> 5;                // slab col 0..63
        const int gc = gi & 31;                // 16B granule within 512B col
        srcb[i] = (unsigned)(rr * 512 + (gc ^ (rr & 7)) * 16);
        ldso[i] = (unsigned)(w * 256 + i * 64) * 16;   // wave-uniform base
    }
    const char* cnbc = (const char*)cnb;

#define ISSUE_STAGE(jj, bi)                                                    \
    do {                                                                       \
        char* bdst_ = (char*)&Bst[bi][0][0];                                   \
        const size_t soff_ = (size_t)(jj) * 32768;                             \
        _Pragma("unroll")                                                      \
        for (int i_ = 0; i_ < 4; ++i_) {                                       \
            __builtin_amdgcn_global_load_lds(                                  \
                (const __attribute__((address_space(1))) void*)(cnbc + soff_ + srcb[i_]), \
                (__attribute__((address_space(3))) void*)(bdst_ + ldso[i_]),   \
                16, 0, 0);                                                     \
        }                                                                      \
    } while (0)

    // prologue: stages 0 and 1 in flight (8 loads per wave)
    ISSUE_STAGE(0, 0);
    ISSUE_STAGE(1, 1);

    // --- A fragments: gathered once from dnb (normalized bf16), pinned
    bf16x8 afr[4][8];
    #pragma unroll
    for (int mt = 0; mt < 4; ++mt) {
        const unsigned short* rb = dnb + (size_t)(r0 + mg * 64 + mt * 16 + lr) * ND + lg * 8;
        #pragma unroll
        for (int kt = 0; kt < 8; ++kt)
            afr[mt][kt] = *(const bf16x8*)(rb + kt * 32);
    }
    #pragma unroll
    for (int mt = 0; mt < 4; ++mt)
        #pragma unroll
        for (int kt = 0; kt < 8; ++kt)
            asm volatile("" : "+v"(afr[mt][kt]));

    float se[4][4], sm[4][4];
    #pragma unroll
    for (int mt = 0; mt < 4; ++mt)
        #pragma unroll
        for (int r = 0; r < 4; ++r) { se[mt][r] = 0.f; sm[mt][r] = 0.f; }

    // own-speaker columns: rows r0+mg*64+mt*16 belong to speaker
    // blk*4 + mg*2 + (mt>>1); column t handled at step j=t>>6, wave ng=(t>>4)&3,
    // lane lr=t&15.
    int town[4];
    #pragma unroll
    for (int mt = 0; mt < 4; ++mt) town[mt] = blk * 4 + mg * 2 + (mt >> 1);

    int bi = 0;   // buffer holding stage j
    for (int j = 0; j < 16; ++j) {
        // counted wait: my 4 loads of stage j done; stage j+1 stays in flight
        if (j < 15) {
            asm volatile("s_waitcnt vmcnt(4)" ::: "memory");
        } else {
            asm volatile("s_waitcnt vmcnt(0)" ::: "memory");
        }
        __builtin_amdgcn_s_barrier();   // all waves' stage-j loads landed

        if (j + 2 < 16) {
            const int nbi = bi + 2 >= 3 ? bi - 1 : bi + 2;   // (bi+2)%3
            ISSUE_STAGE(j + 2, nbi);
        }

        const unsigned short (*bc)[256] = Bst[bi];
        f32x4 acc[4];
        #pragma unroll
        for (int mt = 0; mt < 4; ++mt) acc[mt] = (f32x4){0.f, 0.f, 0.f, 0.f};

        #pragma unroll
        for (int kt = 0; kt < 8; ++kt) {
            const bf16x8 bfr = *(const bf16x8*)&bc[ng * 16 + lr][((kt * 4 + lg) ^ rsw) * 8];
            #pragma unroll
            for (int mt = 0; mt < 4; ++mt)
                acc[mt] = __builtin_amdgcn_mfma_f32_16x16x32_bf16(afr[mt][kt], bfr, acc[mt], 0, 0, 0);
        }

        // branchless fixed-reference fold (cos <= 1 => reference max = 1)
        #pragma unroll
        for (int mt = 0; mt < 4; ++mt)
            #pragma unroll
            for (int r = 0; r < 4; ++r) {
                const float cv = acc[mt][r];
                se[mt][r] += EXP2F(fmaf(c2, cv, -c2));
                sm[mt][r] += cv;
            }

        // own-speaker column subtract (wave-uniform j/ng tests, lane lr test)
        #pragma unroll
        for (int mt = 0; mt < 4; ++mt) {
            const int tn = town[mt];
            if ((tn >> 6) == j && ((tn >> 4) & 3) == ng) {
                if (lr == (tn & 15)) {
                    #pragma unroll
                    for (int r = 0; r < 4; ++r) {
                        const float cv = acc[mt][r];
                        se[mt][r] -= EXP2F(fmaf(c2, cv, -c2));
                        sm[mt][r] -= cv;
                    }
                }
            }
        }

        bi = bi + 1 >= 3 ? 0 : bi + 1;   // (bi+1)%3
    }
#undef ISSUE_STAGE

    // reduce across the 16 column-lanes (xor bits 0..3)
    #pragma unroll
    for (int mask = 1; mask <= 8; mask <<= 1)
        #pragma unroll
        for (int mt = 0; mt < 4; ++mt)
            #pragma unroll
            for (int r = 0; r < 4; ++r) {
                se[mt][r] += __shfl_xor(se[mt][r], mask, 64);
                sm[mt][r] += __shfl_xor(sm[mt][r], mask, 64);
            }

    if (lr == 0) {
        #pragma unroll
        for (int mt = 0; mt < 4; ++mt)
            #pragma unroll
            for (int r = 0; r < 4; ++r) {
                const int row = mg * 64 + mt * 16 + lg * 4 + r;
                pse[ng][row] = se[mt][r];
                psm[ng][row] = sm[mt][r];
            }
    }
    __syncthreads();

    if (tid < BM) {
        const float st = pse[0][tid] + pse[1][tid] + pse[2][tid] + pse[3][tid];
        float smt = psm[0][tid] + psm[1][tid] + psm[2][tid] + psm[3][tid];
        float lse = w0 + b0 + __logf(st);
        #pragma unroll
        for (int mask = 1; mask <= 32; mask <<= 1) {
            lse += __shfl_xor(lse, mask, 64);
            smt += __shfl_xor(smt, mask, 64);
        }
        if ((tid & 63) == 0) { redn[tid >> 6] = smt; redl[tid >> 6] = lse; }
    }
    __syncthreads();
    if (tid == 0) {
        blk_neg[blk] = redn[0] + redn[1];
        blk_lse[blk] = redl[0] + redl[1];
    }
}

// ---------------------------------------------------------------------------
// Kernel 3: final reduction -> (loss, pos_mean, neg_mean)
// ---------------------------------------------------------------------------
__global__ __launch_bounds__(256) void ge2e_k3(
    const float* __restrict__ blk_pos, const float* __restrict__ blk_neg,
    const float* __restrict__ blk_lse, const float* __restrict__ wp,
    const float* __restrict__ bp, float* __restrict__ out)
{
    const int tid = threadIdx.x;
    __shared__ float red[12];
    float p = 0.f, n = 0.f, l = 0.f;
    for (int i = tid; i < NS; i += 256) p += blk_pos[i];
    for (int i = tid; i < NBLK; i += 256) { n += blk_neg[i]; l += blk_lse[i]; }
    #pragma unroll
    for (int off = 32; off > 0; off >>= 1) {
        p += __shfl_xor(p, off, 64);
        n += __shfl_xor(n, off, 64);
        l += __shfl_xor(l, off, 64);
    }
    const int wave = tid >> 6, lane = tid & 63;
    if (lane == 0) { red[wave] = p; red[4 + wave] = n; red[8 + wave] = l; }
    __syncthreads();
    if (tid == 0) {
        const float ps = red[0] + red[1] + red[2] + red[3];
        const float ns = red[4] + red[5] + red[6] + red[7];
        const float ls = red[8] + red[9] + red[10] + red[11];
        const float pos_mean = ps * (1.0f / NROWS);
        const float neg_mean = ns / ((float)NS * (float)NU * (float)(NS - 1));
        const float lse_mean = ls * (1.0f / NROWS);
        const float loss = -(wp[0] * pos_mean + bp[0]) + lse_mean;
        out[0] = loss;
        out[1] = pos_mean;
        out[2] = neg_mean;
    }
}

extern "C" void kernel_launch(void* const* d_in, const int* in_sizes, int n_in,
                              void* d_out, int out_size, void* d_ws, size_t ws_size,
                              hipStream_t stream)
{
    const float* dv = (const float*)d_in[0];
    const float* w  = (const float*)d_in[1];
    const float* b  = (const float*)d_in[2];
    float* out = (float*)d_out;

    unsigned short* cnb = (unsigned short*)d_ws;           // [NS][ND] bf16, 512 KB
    unsigned short* dnb = cnb + (size_t)NS * ND;           // [NROWS][ND] bf16, 16.8 MB
    float* blk_pos = (float*)(dnb + (size_t)NROWS * ND);   // [NS]
    float* blk_neg = blk_pos + NS;                         // [NBLK]
    float* blk_lse = blk_neg + NBLK;                       // [NBLK]

    hipLaunchKernelGGL(ge2e_k1, dim3(NS), dim3(256), 0, stream,
                       dv, cnb, dnb, blk_pos);
    hipLaunchKernelGGL(ge2e_k2, dim3(NBLK), dim3(512), 0, stream,
                       dnb, cnb, w, b, blk_neg, blk_lse);
    hipLaunchKernelGGL(ge2e_k3, dim3(1), dim3(256), 0, stream,
                       blk_pos, blk_neg, blk_lse, w, b, out);
}

// Round 10
// 53.103 us; speedup vs baseline: 1.0897x; 1.0897x over previous
//
#include <hip/hip_runtime.h>
#include <math.h>

#define NS 1024
#define NU 32
#define ND 256
#define NROWS (NS * NU)             // 32768
#define BM 128                      // rows per k2 block
#define NBLK (NROWS / BM)           // 256 blocks, full 1024 cols each

static constexpr float EPS_POS = 1e-6f;
static constexpr float EPS_NEG = 1e-8f;

typedef __attribute__((ext_vector_type(8))) short bf16x8;
typedef __attribute__((ext_vector_type(4))) float f32x4;

#if __has_builtin(__builtin_amdgcn_exp2f)
#define EXP2F(x) __builtin_amdgcn_exp2f(x)
#else
#define EXP2F(x) exp2f(x)
#endif

static __device__ __forceinline__ unsigned short f2bf(float f) {
    union { float f; unsigned u; } v; v.f = f;
    unsigned r = v.u + 0x7fffu + ((v.u >> 16) & 1u);   // RNE
    return (unsigned short)(r >> 16);
}

// ---------------------------------------------------------------------------
// Kernel 1: per-speaker centroids (-> bf16 normalized cnb[t][d]), positive
// (LOO) cosines, and NORMALIZED bf16 ROWS dnb[r][d]. One block per speaker.
// ---------------------------------------------------------------------------
__global__ __launch_bounds__(256) void ge2e_k1(
    const float* __restrict__ dv, unsigned short* __restrict__ cnb,
    unsigned short* __restrict__ dnb, float* __restrict__ blk_pos)
{
    const int s = blockIdx.x;
    const int tid = threadIdx.x;
    const int wave = tid >> 6;
    const int lane = tid & 63;

    __shared__ float v[NU][ND];
    __shared__ float cs[ND];
    __shared__ float sinvs[NU];
    __shared__ float red[16];

    const float* base = dv + (size_t)s * (NU * ND);
    for (int idx = tid; idx < NU * ND; idx += 256) {
        v[idx >> 8][idx & 255] = base[idx];
    }
    __syncthreads();

    {
        float a = 0.f;
        #pragma unroll
        for (int u = 0; u < NU; ++u) a += v[u][tid];
        cs[tid] = a;
    }
    __syncthreads();

    // centroid norm -> normalized centroid in bf16, row-major [t][d]
    float c = cs[tid] * (1.0f / NU);
    float p = c * c;
    #pragma unroll
    for (int off = 32; off > 0; off >>= 1) p += __shfl_xor(p, off, 64);
    if (lane == 0) red[wave] = p;
    __syncthreads();
    if (tid == 0) red[8] = red[0] + red[1] + red[2] + red[3];
    __syncthreads();
    {
        float rn = 1.0f / fmaxf(sqrtf(red[8]), EPS_NEG);
        cnb[(size_t)s * ND + tid] = f2bf(c * rn);
    }

    // per-utterance stats: wave w handles u = 8w .. 8w+7
    const float inv31 = 1.0f / (NU - 1);
    float pos_part = 0.f;
    const float4 cc = *(const float4*)&cs[lane * 4];
    for (int uu = 0; uu < 8; ++uu) {
        const int u = wave * 8 + uu;
        const float4 vv = *(const float4*)&v[u][lane * 4];
        float pv = 0.f, pp = 0.f, px = 0.f;
        float pc;
        pc = (cc.x - vv.x) * inv31; pv += vv.x * vv.x; pp += pc * pc; px += vv.x * pc;
        pc = (cc.y - vv.y) * inv31; pv += vv.y * vv.y; pp += pc * pc; px += vv.y * pc;
        pc = (cc.z - vv.z) * inv31; pv += vv.z * vv.z; pp += pc * pc; px += vv.z * pc;
        pc = (cc.w - vv.w) * inv31; pv += vv.w * vv.w; pp += pc * pc; px += vv.w * pc;
        #pragma unroll
        for (int off = 32; off > 0; off >>= 1) {
            pv += __shfl_xor(pv, off, 64);
            pp += __shfl_xor(pp, off, 64);
            px += __shfl_xor(px, off, 64);
        }
        if (lane == 0) {
            float nv = sqrtf(pv), npc = sqrtf(pp);
            pos_part += px / (fmaxf(nv, EPS_POS) * fmaxf(npc, EPS_POS));
            sinvs[u] = 1.0f / fmaxf(nv, EPS_NEG);
        }
    }
    if (lane == 0) red[4 + wave] = pos_part;
    __syncthreads();
    if (tid == 0) blk_pos[s] = red[4] + red[5] + red[6] + red[7];

    // normalized bf16 rows -> global (coalesced 16B stores)
    #pragma unroll
    for (int it = 0; it < 4; ++it) {
        const int idx = it * 2048 + tid * 8;
        const int u = idx >> 8, d0 = idx & 255;
        const float sc = sinvs[u];
        uint4 pk;
        pk.x = (unsigned)f2bf(v[u][d0 + 0] * sc) | ((unsigned)f2bf(v[u][d0 + 1] * sc) << 16);
        pk.y = (unsigned)f2bf(v[u][d0 + 2] * sc) | ((unsigned)f2bf(v[u][d0 + 3] * sc) << 16);
        pk.z = (unsigned)f2bf(v[u][d0 + 4] * sc) | ((unsigned)f2bf(v[u][d0 + 5] * sc) << 16);
        pk.w = (unsigned)f2bf(v[u][d0 + 6] * sc) | ((unsigned)f2bf(v[u][d0 + 7] * sc) << 16);
        *(uint4*)&dnb[(size_t)s * (NU * ND) + idx] = pk;
    }
}

// ---------------------------------------------------------------------------
// Kernel 2: MFMA GEMM, BM=128 rows x ALL 1024 cols, K=256, fused sum-exp
// epilogue. 256 blocks x 512 threads (8 waves = 2 mg x 4 ng, mt=4).
// afr[4][8] pinned in registers from dnb.
// KEY FIX vs R9: THREE SEPARATE __shared__ buffers + 16 steps fully unrolled
// with LITERAL buffer names -> LLVM alias analysis proves global_load_lds
// writes never touch the buffer being ds_read -> no conservative
// s_waitcnt vmcnt(0) before the reads (the serializer in R3-R9).
// Counted vmcnt(4) + raw s_barrier, depth-2 prefetch, setprio around MFMA.
// ---------------------------------------------------------------------------
__global__ __launch_bounds__(512, 2) void ge2e_k2(
    const unsigned short* __restrict__ dnb, const unsigned short* __restrict__ cnb,
    const float* __restrict__ wp, const float* __restrict__ bp,
    float* __restrict__ blk_neg, float* __restrict__ blk_lse)
{
    const int blk = blockIdx.x;
    const int r0 = blk * BM;
    const int tid = threadIdx.x;
    const int w  = tid >> 6;
    const int l  = tid & 63;
    const int lr = l & 15;
    const int lg = l >> 4;
    const int mg = w >> 2;   // 0..1: rows mg*64 .. +64
    const int ng = w & 3;    // 0..3: cols j*64 + ng*16 .. +16
    const int rsw = lr & 7;

    __shared__ unsigned short Bst0[64][256];   // 32 KB each, alias-distinct
    __shared__ unsigned short Bst1[64][256];
    __shared__ unsigned short Bst2[64][256];
    __shared__ float pse[4][BM];
    __shared__ float psm[4][BM];
    __shared__ float redn[2], redl[2];

    const float w0 = wp[0];
    const float b0 = bp[0];
    const float c2 = w0 * 1.4426950408889634f;   // w0 * log2(e)

    // --- B stage addressing: per-lane pre-swizzled global src, linear LDS.
    // Slab = 64 cols x 256 k = 32 KB = 2048 granules of 16B; 512 thr x 4.
    unsigned srcb[4], ldso[4];
    #pragma unroll
    for (int i = 0; i < 4; ++i) {
        const int gi = w * 256 + i * 64 + l;   // granule 0..2047 of the slab
        const int rr = gi >> 5;                // slab col 0..63
        const int gc = gi & 31;                // 16B granule within 512B col
        srcb[i] = (unsigned)(rr * 512 + (gc ^ (rr & 7)) * 16);
        ldso[i] = (unsigned)(w * 256 + i * 64) * 16;   // wave-uniform base
    }
    const char* cnbc = (const char*)cnb;

#define ISSUE_STAGE(JJ, BUF)                                                   \
    do {                                                                       \
        char* bdst_ = (char*)&BUF[0][0];                                       \
        const size_t soff_ = (size_t)(JJ) * 32768;                             \
        _Pragma("unroll")                                                      \
        for (int i_ = 0; i_ < 4; ++i_) {                                       \
            __builtin_amdgcn_global_load_lds(                                  \
                (const __attribute__((address_space(1))) void*)(cnbc + soff_ + srcb[i_]), \
                (__attribute__((address_space(3))) void*)(bdst_ + ldso[i_]),   \
                16, 0, 0);                                                     \
        }                                                                      \
    } while (0)

    // prologue: stages 0 and 1 in flight (8 loads per wave)
    ISSUE_STAGE(0, Bst0);
    ISSUE_STAGE(1, Bst1);

    // --- A fragments: gathered once from dnb (normalized bf16), pinned
    bf16x8 afr[4][8];
    #pragma unroll
    for (int mt = 0; mt < 4; ++mt) {
        const unsigned short* rb = dnb + (size_t)(r0 + mg * 64 + mt * 16 + lr) * ND + lg * 8;
        #pragma unroll
        for (int kt = 0; kt < 8; ++kt)
            afr[mt][kt] = *(const bf16x8*)(rb + kt * 32);
    }
    #pragma unroll
    for (int mt = 0; mt < 4; ++mt)
        #pragma unroll
        for (int kt = 0; kt < 8; ++kt)
            asm volatile("" : "+v"(afr[mt][kt]));

    float se[4][4], sm[4][4];
    #pragma unroll
    for (int mt = 0; mt < 4; ++mt)
        #pragma unroll
        for (int r = 0; r < 4; ++r) { se[mt][r] = 0.f; sm[mt][r] = 0.f; }

    // own-speaker columns: rows r0+mg*64+mt*16 belong to speaker
    // blk*4 + mg*2 + (mt>>1); col t handled at step j=t>>6, wave ng=(t>>4)&3,
    // lane lr=t&15.
    int town[4];
    #pragma unroll
    for (int mt = 0; mt < 4; ++mt) town[mt] = blk * 4 + mg * 2 + (mt >> 1);

#define K2_STEP(J, BR, BW, DOISSUE, LASTWAIT)                                  \
    do {                                                                       \
        if (LASTWAIT) { asm volatile("s_waitcnt vmcnt(0)" ::: "memory"); }     \
        else          { asm volatile("s_waitcnt vmcnt(4)" ::: "memory"); }     \
        __builtin_amdgcn_s_barrier();                                          \
        if (DOISSUE) ISSUE_STAGE((J) + 2, BW);                                 \
        f32x4 acc[4];                                                          \
        _Pragma("unroll")                                                      \
        for (int mt_ = 0; mt_ < 4; ++mt_) acc[mt_] = (f32x4){0.f, 0.f, 0.f, 0.f}; \
        __builtin_amdgcn_s_setprio(1);                                         \
        _Pragma("unroll")                                                      \
        for (int kt_ = 0; kt_ < 8; ++kt_) {                                    \
            const bf16x8 bfr = *(const bf16x8*)&BR[ng * 16 + lr][((kt_ * 4 + lg) ^ rsw) * 8]; \
            acc[0] = __builtin_amdgcn_mfma_f32_16x16x32_bf16(afr[0][kt_], bfr, acc[0], 0, 0, 0); \
            acc[1] = __builtin_amdgcn_mfma_f32_16x16x32_bf16(afr[1][kt_], bfr, acc[1], 0, 0, 0); \
            acc[2] = __builtin_amdgcn_mfma_f32_16x16x32_bf16(afr[2][kt_], bfr, acc[2], 0, 0, 0); \
            acc[3] = __builtin_amdgcn_mfma_f32_16x16x32_bf16(afr[3][kt_], bfr, acc[3], 0, 0, 0); \
        }                                                                      \
        __builtin_amdgcn_s_setprio(0);                                         \
        _Pragma("unroll")                                                      \
        for (int mt_ = 0; mt_ < 4; ++mt_)                                      \
            _Pragma("unroll")                                                  \
            for (int r_ = 0; r_ < 4; ++r_) {                                   \
                const float cv_ = acc[mt_][r_];                                \
                se[mt_][r_] += EXP2F(fmaf(c2, cv_, -c2));                      \
                sm[mt_][r_] += cv_;                                            \
            }                                                                  \
        _Pragma("unroll")                                                      \
        for (int mt_ = 0; mt_ < 4; ++mt_) {                                    \
            const int tn_ = town[mt_];                                         \
            if ((tn_ >> 6) == (J) && ((tn_ >> 4) & 3) == ng) {                 \
                if (lr == (tn_ & 15)) {                                        \
                    _Pragma("unroll")                                          \
                    for (int r_ = 0; r_ < 4; ++r_) {                           \
                        const float cv_ = acc[mt_][r_];                        \
                        se[mt_][r_] -= EXP2F(fmaf(c2, cv_, -c2));              \
                        sm[mt_][r_] -= cv_;                                    \
                    }                                                          \
                }                                                              \
            }                                                                  \
        }                                                                      \
    } while (0)

    // 16 steps, buffer of stage s = Bst(s%3); step J reads s=J, writes s=J+2
    K2_STEP( 0, Bst0, Bst2, 1, 0);
    K2_STEP( 1, Bst1, Bst0, 1, 0);
    K2_STEP( 2, Bst2, Bst1, 1, 0);
    K2_STEP( 3, Bst0, Bst2, 1, 0);
    K2_STEP( 4, Bst1, Bst0, 1, 0);
    K2_STEP( 5, Bst2, Bst1, 1, 0);
    K2_STEP( 6, Bst0, Bst2, 1, 0);
    K2_STEP( 7, Bst1, Bst0, 1, 0);
    K2_STEP( 8, Bst2, Bst1, 1, 0);
    K2_STEP( 9, Bst0, Bst2, 1, 0);
    K2_STEP(10, Bst1, Bst0, 1, 0);
    K2_STEP(11, Bst2, Bst1, 1, 0);
    K2_STEP(12, Bst0, Bst2, 1, 0);
    K2_STEP(13, Bst1, Bst0, 1, 0);
    K2_STEP(14, Bst2, Bst0, 0, 0);   // no issue; vmcnt(4) waits stage 14
    K2_STEP(15, Bst0, Bst1, 0, 1);   // vmcnt(0) waits stage 15
#undef K2_STEP
#undef ISSUE_STAGE

    // reduce across the 16 column-lanes (xor bits 0..3)
    #pragma unroll
    for (int mask = 1; mask <= 8; mask <<= 1)
        #pragma unroll
        for (int mt = 0; mt < 4; ++mt)
            #pragma unroll
            for (int r = 0; r < 4; ++r) {
                se[mt][r] += __shfl_xor(se[mt][r], mask, 64);
                sm[mt][r] += __shfl_xor(sm[mt][r], mask, 64);
            }

    if (lr == 0) {
        #pragma unroll
        for (int mt = 0; mt < 4; ++mt)
            #pragma unroll
            for (int r = 0; r < 4; ++r) {
                const int row = mg * 64 + mt * 16 + lg * 4 + r;
                pse[ng][row] = se[mt][r];
                psm[ng][row] = sm[mt][r];
            }
    }
    __syncthreads();

    if (tid < BM) {
        const float st = pse[0][tid] + pse[1][tid] + pse[2][tid] + pse[3][tid];
        float smt = psm[0][tid] + psm[1][tid] + psm[2][tid] + psm[3][tid];
        float lse = w0 + b0 + __logf(st);
        #pragma unroll
        for (int mask = 1; mask <= 32; mask <<= 1) {
            lse += __shfl_xor(lse, mask, 64);
            smt += __shfl_xor(smt, mask, 64);
        }
        if ((tid & 63) == 0) { redn[tid >> 6] = smt; redl[tid >> 6] = lse; }
    }
    __syncthreads();
    if (tid == 0) {
        blk_neg[blk] = redn[0] + redn[1];
        blk_lse[blk] = redl[0] + redl[1];
    }
}

// ---------------------------------------------------------------------------
// Kernel 3: final reduction -> (loss, pos_mean, neg_mean)
// ---------------------------------------------------------------------------
__global__ __launch_bounds__(256) void ge2e_k3(
    const float* __restrict__ blk_pos, const float* __restrict__ blk_neg,
    const float* __restrict__ blk_lse, const float* __restrict__ wp,
    const float* __restrict__ bp, float* __restrict__ out)
{
    const int tid = threadIdx.x;
    __shared__ float red[12];
    float p = 0.f, n = 0.f, l = 0.f;
    for (int i = tid; i < NS; i += 256) p += blk_pos[i];
    for (int i = tid; i < NBLK; i += 256) { n += blk_neg[i]; l += blk_lse[i]; }
    #pragma unroll
    for (int off = 32; off > 0; off >>= 1) {
        p += __shfl_xor(p, off, 64);
        n += __shfl_xor(n, off, 64);
        l += __shfl_xor(l, off, 64);
    }
    const int wave = tid >> 6, lane = tid & 63;
    if (lane == 0) { red[wave] = p; red[4 + wave] = n; red[8 + wave] = l; }
    __syncthreads();
    if (tid == 0) {
        const float ps = red[0] + red[1] + red[2] + red[3];
        const float ns = red[4] + red[5] + red[6] + red[7];
        const float ls = red[8] + red[9] + red[10] + red[11];
        const float pos_mean = ps * (1.0f / NROWS);
        const float neg_mean = ns / ((float)NS * (float)NU * (float)(NS - 1));
        const float lse_mean = ls * (1.0f / NROWS);
        const float loss = -(wp[0] * pos_mean + bp[0]) + lse_mean;
        out[0] = loss;
        out[1] = pos_mean;
        out[2] = neg_mean;
    }
}

extern "C" void kernel_launch(void* const* d_in, const int* in_sizes, int n_in,
                              void* d_out, int out_size, void* d_ws, size_t ws_size,
                              hipStream_t stream)
{
    const float* dv = (const float*)d_in[0];
    const float* w  = (const float*)d_in[1];
    const float* b  = (const float*)d_in[2];
    float* out = (float*)d_out;

    unsigned short* cnb = (unsigned short*)d_ws;           // [NS][ND] bf16, 512 KB
    unsigned short* dnb = cnb + (size_t)NS * ND;           // [NROWS][ND] bf16, 16.8 MB
    float* blk_pos = (float*)(dnb + (size_t)NROWS * ND);   // [NS]
    float* blk_neg = blk_pos + NS;                         // [NBLK]
    float* blk_lse = blk_neg + NBLK;                       // [NBLK]

    hipLaunchKernelGGL(ge2e_k1, dim3(NS), dim3(256), 0, stream,
                       dv, cnb, dnb, blk_pos);
    hipLaunchKernelGGL(ge2e_k2, dim3(NBLK), dim3(512), 0, stream,
                       dnb, cnb, w, b, blk_neg, blk_lse);
    hipLaunchKernelGGL(ge2e_k3, dim3(1), dim3(256), 0, stream,
                       blk_pos, blk_neg, blk_lse, w, b, out);
}